// Round 3
// baseline (531.461 us; speedup 1.0000x reference)
//
#include <hip/hip_runtime.h>
#include <math.h>

// B=4, L=32, HP=32, H=64, W=64, D=32, DFFN=64
// Fused persistent kernel: 256 blocks x 256 threads (1 block/CU, co-resident),
// grid barriers between phases via device-scope atomics in d_ws.

#define NBLK 256

__device__ __forceinline__ float sigf(float v) { return 1.0f / (1.0f + __expf(-v)); }
__device__ __forceinline__ float bl(float v, int l) {
    return __int_as_float(__builtin_amdgcn_readlane(__float_as_int(v), l));
}

// grid barrier: counter zeroed host-side (memset node) before every launch
__device__ __forceinline__ void gbar(unsigned* c) {
    __threadfence();            // release this block's global writes (agent scope)
    __syncthreads();
    if (threadIdx.x == 0) {
        __hip_atomic_fetch_add(c, 1u, __ATOMIC_ACQ_REL, __HIP_MEMORY_SCOPE_AGENT);
        while (__hip_atomic_load(c, __ATOMIC_ACQUIRE, __HIP_MEMORY_SCOPE_AGENT) < NBLK)
            __builtin_amdgcn_s_sleep(1);
    }
    __syncthreads();
    __threadfence();            // acquire side for all threads
}

__global__ __launch_bounds__(256, 1) void k_fused(
    const float* __restrict__ x, const float* __restrict__ in_proj_w,
    const float* __restrict__ in_proj_b, const float* __restrict__ layer_emb,
    const float* __restrict__ time_decay, const float* __restrict__ time_first,
    const float* __restrict__ ln_tm_g, const float* __restrict__ ln_tm_b,
    const float* __restrict__ tm_r, const float* __restrict__ tm_k,
    const float* __restrict__ tm_v, const float* __restrict__ tm_out,
    const float* __restrict__ ln_cm_g, const float* __restrict__ ln_cm_b,
    const float* __restrict__ cm_k, const float* __restrict__ cm_v,
    const float* __restrict__ cm_r,
    const float* __restrict__ gate_w, const float* __restrict__ gate_b,
    const float* __restrict__ row_w, const float* __restrict__ row_b,
    const float* __restrict__ col_w, const float* __restrict__ col_b,
    float* __restrict__ out, float* __restrict__ wsf)
{
    float* feat  = wsf;              // 131072 floats  [l][b][hp][d]
    float* fy    = wsf + 131072;     // 131072 floats
    float* gpart = wsf + 262144;     // 256
    float* mpart = wsf + 262400;     // 256
    unsigned* cnt = (unsigned*)(wsf + 262656);  // 3 barrier counters (memset to 0)

    const int bid = blockIdx.x;
    const int t   = threadIdx.x;

    // ======================= Phase 1: stats + in_proj =======================
    {
        __shared__ float red[4][9];
        __shared__ float tot[9];
        for (int it16 = 0; it16 < 16; ++it16) {
            const int g = bid + (it16 << 8);
            const int hp = g & 31, l = (g >> 5) & 31, bb = g >> 10;
            const float4* pa = (const float4*)(x + (size_t)(bb * 2048 + l * 32 + hp) * 4096);
            const float4* pb = (const float4*)(x + (size_t)(bb * 2048 + 1024 + l * 32 + hp) * 4096);

            float sa = 0.f, saa = 0.f, sb = 0.f, sbb = 0.f, sab = 0.f;
            float mna = 3.4e38f, mxa = -3.4e38f, mnb = 3.4e38f, mxb = -3.4e38f;
#pragma unroll
            for (int it = 0; it < 4; ++it) {
                float4 a4 = pa[t + it * 256];
                float4 b4 = pb[t + it * 256];
                sa  += a4.x + a4.y + a4.z + a4.w;
                sb  += b4.x + b4.y + b4.z + b4.w;
                saa += a4.x * a4.x + a4.y * a4.y + a4.z * a4.z + a4.w * a4.w;
                sbb += b4.x * b4.x + b4.y * b4.y + b4.z * b4.z + b4.w * b4.w;
                sab += a4.x * b4.x + a4.y * b4.y + a4.z * b4.z + a4.w * b4.w;
                mna = fminf(mna, fminf(fminf(a4.x, a4.y), fminf(a4.z, a4.w)));
                mxa = fmaxf(mxa, fmaxf(fmaxf(a4.x, a4.y), fmaxf(a4.z, a4.w)));
                mnb = fminf(mnb, fminf(fminf(b4.x, b4.y), fminf(b4.z, b4.w)));
                mxb = fmaxf(mxb, fmaxf(fmaxf(b4.x, b4.y), fmaxf(b4.z, b4.w)));
            }
#pragma unroll
            for (int m = 1; m < 64; m <<= 1) {
                sa  += __shfl_xor(sa, m);
                saa += __shfl_xor(saa, m);
                sb  += __shfl_xor(sb, m);
                sbb += __shfl_xor(sbb, m);
                sab += __shfl_xor(sab, m);
                mna = fminf(mna, __shfl_xor(mna, m));
                mxa = fmaxf(mxa, __shfl_xor(mxa, m));
                mnb = fminf(mnb, __shfl_xor(mnb, m));
                mxb = fmaxf(mxb, __shfl_xor(mxb, m));
            }
            const int lane = t & 63, wv = t >> 6;
            if (lane == 0) {
                red[wv][0] = sa;  red[wv][1] = saa; red[wv][2] = sb;  red[wv][3] = sbb;
                red[wv][4] = sab; red[wv][5] = mna; red[wv][6] = mxa; red[wv][7] = mnb;
                red[wv][8] = mxb;
            }
            __syncthreads();
            if (t == 0) {
#pragma unroll
                for (int q = 0; q < 5; ++q) tot[q] = red[0][q] + red[1][q] + red[2][q] + red[3][q];
                tot[5] = fminf(fminf(red[0][5], red[1][5]), fminf(red[2][5], red[3][5]));
                tot[6] = fmaxf(fmaxf(red[0][6], red[1][6]), fmaxf(red[2][6], red[3][6]));
                tot[7] = fminf(fminf(red[0][7], red[1][7]), fminf(red[2][7], red[3][7]));
                tot[8] = fmaxf(fmaxf(red[0][8], red[1][8]), fmaxf(red[2][8], red[3][8]));
            }
            __syncthreads();
            if (t < 32) {
                const float SA = tot[0], SAA = tot[1], SB = tot[2], SBB = tot[3], SAB = tot[4];
                const float inv_n = 1.f / 4096.f, inv_nm1 = 1.f / 4095.f;
                float st[12];
                st[0] = SA * inv_n;
                st[1] = sqrtf(fmaxf(SAA - SA * SA * inv_n, 0.f) * inv_nm1);
                st[2] = tot[5]; st[3] = tot[6];
                st[4] = SB * inv_n;
                st[5] = sqrtf(fmaxf(SBB - SB * SB * inv_n, 0.f) * inv_nm1);
                st[6] = tot[7]; st[7] = tot[8];
                const float SD = SA - SB, SDD = SAA - 2.f * SAB + SBB;
                st[8]  = SD * inv_n;
                st[9]  = sqrtf(fmaxf(SDD - SD * SD * inv_n, 0.f) * inv_nm1);
                st[10] = sqrtf(fmaxf(SDD, 0.f));
                const float na = fmaxf(sqrtf(SAA), 1e-8f), nb2 = fmaxf(sqrtf(SBB), 1e-8f);
                st[11] = SAB / (na * nb2);
                float acc = in_proj_b[t] + layer_emb[l * 32 + t];
#pragma unroll
                for (int s2 = 0; s2 < 12; ++s2) acc += st[s2] * in_proj_w[t * 12 + s2];
                feat[((l * 4 + bb) * 32 + hp) * 32 + t] = acc;
            }
            __syncthreads();
        }
    }
    gbar(&cnt[0]);

    // ======================= Phase 2: RWKV scan (blocks 0..31) ==============
    if (bid < 32) {
        const int lane = t & 63;
        const int d = lane & 31;
        const int wv = t >> 6;
        const int seq = bid * 4 + wv;            // 0..127
        const int bb = seq >> 5, hp = seq & 31;

        float w_r[32], w_k[32], w_v[32], w_o[32], w_cr[32], w_ck[32], w_cv[64];
        {
            const float4* pr = (const float4*)(tm_r  + d * 32);
            const float4* pk = (const float4*)(tm_k  + d * 32);
            const float4* pv = (const float4*)(tm_v  + d * 32);
            const float4* po = (const float4*)(tm_out + d * 32);
            const float4* pc = (const float4*)(cm_r  + d * 32);
            const float4* pq = (const float4*)(cm_k  + lane * 32);
            const float4* pw = (const float4*)(cm_v  + d * 64);
#pragma unroll
            for (int jq = 0; jq < 8; ++jq) {
                float4 v;
                v = pr[jq]; w_r[4*jq] = v.x; w_r[4*jq+1] = v.y; w_r[4*jq+2] = v.z; w_r[4*jq+3] = v.w;
                v = pk[jq]; w_k[4*jq] = v.x; w_k[4*jq+1] = v.y; w_k[4*jq+2] = v.z; w_k[4*jq+3] = v.w;
                v = pv[jq]; w_v[4*jq] = v.x; w_v[4*jq+1] = v.y; w_v[4*jq+2] = v.z; w_v[4*jq+3] = v.w;
                v = po[jq]; w_o[4*jq] = v.x; w_o[4*jq+1] = v.y; w_o[4*jq+2] = v.z; w_o[4*jq+3] = v.w;
                v = pc[jq]; w_cr[4*jq] = v.x; w_cr[4*jq+1] = v.y; w_cr[4*jq+2] = v.z; w_cr[4*jq+3] = v.w;
                v = pq[jq]; w_ck[4*jq] = v.x; w_ck[4*jq+1] = v.y; w_ck[4*jq+2] = v.z; w_ck[4*jq+3] = v.w;
            }
#pragma unroll
            for (int jq = 0; jq < 16; ++jq) {
                float4 v = pw[jq];
                w_cv[4*jq] = v.x; w_cv[4*jq+1] = v.y; w_cv[4*jq+2] = v.z; w_cv[4*jq+3] = v.w;
            }
        }
        const float gt = ln_tm_g[d], bt = ln_tm_b[d];
        const float gc = ln_cm_g[d], bc = ln_cm_b[d];
        const float tf = time_first[d];
        const float wd = __expf(time_decay[d]);
        const int base = (bb * 32 + hp) * 32 + d;

        float aa = 0.f, bbs = 0.f, pp = -1e30f;
        float f = feat[base];

        for (int l = 0; l < 32; ++l) {
            float fnext = 0.f;
            if (l < 31) fnext = feat[base + (l + 1) * 4096];
            // LN1 (fused mean / mean-sq tree, width 32)
            float s = f, q = f * f;
#pragma unroll
            for (int m = 1; m < 32; m <<= 1) { s += __shfl_xor(s, m, 32); q += __shfl_xor(q, m, 32); }
            const float mu = s * (1.f / 32.f);
            const float var = fmaxf(q * (1.f / 32.f) - mu * mu, 0.f);
            const float xn = (f - mu) * rsqrtf(var + 1e-5f) * gt + bt;
            // r,k,v matvecs: 4-way split accumulators (short FMA chains)
            float r0 = 0.f, r1 = 0.f, r2 = 0.f, r3 = 0.f;
            float k0 = 0.f, k1 = 0.f, k2 = 0.f, k3 = 0.f;
            float v0 = 0.f, v1 = 0.f, v2 = 0.f, v3 = 0.f;
#pragma unroll
            for (int j = 0; j < 8; ++j) {
                const float x0 = bl(xn, j), x1 = bl(xn, j + 8), x2 = bl(xn, j + 16), x3 = bl(xn, j + 24);
                r0 += x0 * w_r[j];      r1 += x1 * w_r[j + 8];
                r2 += x2 * w_r[j + 16]; r3 += x3 * w_r[j + 24];
                k0 += x0 * w_k[j];      k1 += x1 * w_k[j + 8];
                k2 += x2 * w_k[j + 16]; k3 += x3 * w_k[j + 24];
                v0 += x0 * w_v[j];      v1 += x1 * w_v[j + 8];
                v2 += x2 * w_v[j + 16]; v3 += x3 * w_v[j + 24];
            }
            const float r = sigf((r0 + r1) + (r2 + r3));
            const float k = (k0 + k1) + (k2 + k3);
            const float v = (v0 + v1) + (v2 + v3);
            // WKV
            const float ww = tf + k;
            const float p = fmaxf(pp, ww);
            const float e1 = __expf(pp - p), e2 = __expf(ww - p);
            const float wkv = (e1 * aa + e2 * v) / fmaxf(e1 * bbs + e2, 1e-8f);
            const float ww2 = pp - wd;
            const float p2 = fmaxf(ww2, k);
            const float e1b = __expf(ww2 - p2), e2b = __expf(k - p2);
            aa = e1b * aa + e2b * v;
            bbs = e1b * bbs + e2b;
            pp = p2;
            // output projection (4-way split)
            float o0 = 0.f, o1 = 0.f, o2 = 0.f, o3 = 0.f;
#pragma unroll
            for (int j = 0; j < 8; ++j) {
                o0 += bl(wkv, j)      * w_o[j];
                o1 += bl(wkv, j + 8)  * w_o[j + 8];
                o2 += bl(wkv, j + 16) * w_o[j + 16];
                o3 += bl(wkv, j + 24) * w_o[j + 24];
            }
            const float y = f + r * ((o0 + o1) + (o2 + o3));
            // LN2
            float s2 = y, q2 = y * y;
#pragma unroll
            for (int m = 1; m < 32; m <<= 1) { s2 += __shfl_xor(s2, m, 32); q2 += __shfl_xor(q2, m, 32); }
            const float mu2 = s2 * (1.f / 32.f);
            const float var2 = fmaxf(q2 * (1.f / 32.f) - mu2 * mu2, 0.f);
            const float xn2 = (y - mu2) * rsqrtf(var2 + 1e-5f) * gc + bc;
            // channel-mix: ck (all 64 lanes, e=lane) + cr, 4-way split
            float c0 = 0.f, c1 = 0.f, c2 = 0.f, c3 = 0.f;
            float g0 = 0.f, g1 = 0.f, g2 = 0.f, g3 = 0.f;
#pragma unroll
            for (int j = 0; j < 8; ++j) {
                const float x0 = bl(xn2, j), x1 = bl(xn2, j + 8), x2 = bl(xn2, j + 16), x3 = bl(xn2, j + 24);
                c0 += x0 * w_ck[j];      c1 += x1 * w_ck[j + 8];
                c2 += x2 * w_ck[j + 16]; c3 += x3 * w_ck[j + 24];
                g0 += x0 * w_cr[j];      g1 += x1 * w_cr[j + 8];
                g2 += x2 * w_cr[j + 16]; g3 += x3 * w_cr[j + 24];
            }
            float kkv = fmaxf((c0 + c1) + (c2 + c3), 0.f);
            kkv *= kkv;
            const float cr = sigf((g0 + g1) + (g2 + g3));
            // cm_v dot over 64 (4-way split)
            float u0 = 0.f, u1 = 0.f, u2 = 0.f, u3 = 0.f;
#pragma unroll
            for (int e = 0; e < 16; ++e) {
                u0 += bl(kkv, e)      * w_cv[e];
                u1 += bl(kkv, e + 16) * w_cv[e + 16];
                u2 += bl(kkv, e + 32) * w_cv[e + 32];
                u3 += bl(kkv, e + 48) * w_cv[e + 48];
            }
            const float y2 = y + cr * ((u0 + u1) + (u2 + u3));
            if (lane < 32) fy[base + l * 4096] = y2;
            f = fnext;
        }
    }
    gbar(&cnt[1]);

    // ======================= Phase 3: mask + merge ==========================
    {
        __shared__ float fs[32];
        __shared__ float row_s[64], col_s[64];
        __shared__ float gate_sh;
        float msum = 0.f, gsum = 0.f;
        for (int it16 = 0; it16 < 16; ++it16) {
            const int g = bid + (it16 << 8);
            const int hp = g & 31, l = (g >> 5) & 31, bb = g >> 10;
            if (t < 32) fs[t] = fy[((l * 4 + bb) * 32 + hp) * 32 + t];
            __syncthreads();
            if (t < 64) {
                float a0 = row_b[t], a1 = 0.f, a2 = 0.f, a3 = 0.f;
#pragma unroll
                for (int d2 = 0; d2 < 8; ++d2) {
                    a0 += fs[d2]      * row_w[t * 32 + d2];
                    a1 += fs[d2 + 8]  * row_w[t * 32 + d2 + 8];
                    a2 += fs[d2 + 16] * row_w[t * 32 + d2 + 16];
                    a3 += fs[d2 + 24] * row_w[t * 32 + d2 + 24];
                }
                row_s[t] = (a0 + a1) + (a2 + a3);
            } else if (t < 128) {
                const int w = t - 64;
                float a0 = col_b[w], a1 = 0.f, a2 = 0.f, a3 = 0.f;
#pragma unroll
                for (int d2 = 0; d2 < 8; ++d2) {
                    a0 += fs[d2]      * col_w[w * 32 + d2];
                    a1 += fs[d2 + 8]  * col_w[w * 32 + d2 + 8];
                    a2 += fs[d2 + 16] * col_w[w * 32 + d2 + 16];
                    a3 += fs[d2 + 24] * col_w[w * 32 + d2 + 24];
                }
                col_s[w] = (a0 + a1) + (a2 + a3);
            } else if (t == 128) {
                float acc = gate_b[0];
#pragma unroll
                for (int d2 = 0; d2 < 32; ++d2) acc += fs[d2] * gate_w[d2];
                gate_sh = acc;
            }
            __syncthreads();
            const float gate = gate_sh;
            if (t == 0) gsum += sigf(gate);
            const float4* pa = (const float4*)(x + (size_t)(bb * 2048 + l * 32 + hp) * 4096);
            const float4* pb = (const float4*)(x + (size_t)(bb * 2048 + 1024 + l * 32 + hp) * 4096);
            float4* po = (float4*)(out + (size_t)(bb * 1024 + l * 32 + hp) * 4096);
#pragma unroll
            for (int it = 0; it < 4; ++it) {
                const int i = t + it * 256;
                const float4 a4 = pa[i];
                const float4 b4 = pb[i];
                const int h = i >> 4, w0 = (i & 15) * 4;
                const float gr = gate + row_s[h];
                const float m0 = sigf(gr + col_s[w0 + 0]);
                const float m1 = sigf(gr + col_s[w0 + 1]);
                const float m2 = sigf(gr + col_s[w0 + 2]);
                const float m3 = sigf(gr + col_s[w0 + 3]);
                float4 o;
                o.x = b4.x + m0 * (a4.x - b4.x);
                o.y = b4.y + m1 * (a4.y - b4.y);
                o.z = b4.z + m2 * (a4.z - b4.z);
                o.w = b4.w + m3 * (a4.w - b4.w);
                po[i] = o;
                msum += m0 + m1 + m2 + m3;
            }
            __syncthreads();
        }
        __shared__ float red2[4];
#pragma unroll
        for (int m = 1; m < 64; m <<= 1) msum += __shfl_xor(msum, m);
        if ((t & 63) == 0) red2[t >> 6] = msum;
        __syncthreads();
        if (t == 0) {
            mpart[bid] = red2[0] + red2[1] + red2[2] + red2[3];
            gpart[bid] = gsum;
        }
    }
    gbar(&cnt[2]);

    // ======================= Phase 4: final scalars (block 0) ===============
    if (bid == 0) {
        __shared__ float rg[4], rm[4];
        float gs = gpart[t], ms = mpart[t];
#pragma unroll
        for (int m = 1; m < 64; m <<= 1) { gs += __shfl_xor(gs, m); ms += __shfl_xor(ms, m); }
        if ((t & 63) == 0) { rg[t >> 6] = gs; rm[t >> 6] = ms; }
        __syncthreads();
        if (t == 0) {
            out[16777216] = (rg[0] + rg[1] + rg[2] + rg[3]) * (1.f / 4096.f);
            out[16777217] = (rm[0] + rm[1] + rm[2] + rm[3]) * (1.f / 16777216.f);
        }
    }
}

extern "C" void kernel_launch(void* const* d_in, const int* in_sizes, int n_in,
                              void* d_out, int out_size, void* d_ws, size_t ws_size,
                              hipStream_t stream) {
    const float* x          = (const float*)d_in[0];
    const float* in_proj_w  = (const float*)d_in[1];
    const float* in_proj_b  = (const float*)d_in[2];
    const float* layer_emb  = (const float*)d_in[3];
    const float* time_decay = (const float*)d_in[4];
    const float* time_first = (const float*)d_in[5];
    const float* ln_tm_g    = (const float*)d_in[6];
    const float* ln_tm_b    = (const float*)d_in[7];
    const float* tm_r       = (const float*)d_in[8];
    const float* tm_k       = (const float*)d_in[9];
    const float* tm_v       = (const float*)d_in[10];
    const float* tm_out     = (const float*)d_in[11];
    const float* ln_cm_g    = (const float*)d_in[12];
    const float* ln_cm_b    = (const float*)d_in[13];
    const float* cm_k       = (const float*)d_in[14];
    const float* cm_v       = (const float*)d_in[15];
    const float* cm_r       = (const float*)d_in[16];
    const float* gate_w     = (const float*)d_in[17];
    const float* gate_b     = (const float*)d_in[18];
    const float* row_w      = (const float*)d_in[19];
    const float* row_b      = (const float*)d_in[20];
    const float* col_w      = (const float*)d_in[21];
    const float* col_b      = (const float*)d_in[22];
    float* out = (float*)d_out;
    float* wsf = (float*)d_ws;

    // zero the 3 grid-barrier counters (ws offset 262656 floats)
    hipMemsetAsync(wsf + 262656, 0, 256, stream);
    k_fused<<<dim3(NBLK), dim3(256), 0, stream>>>(
        x, in_proj_w, in_proj_b, layer_emb, time_decay, time_first,
        ln_tm_g, ln_tm_b, tm_r, tm_k, tm_v, tm_out,
        ln_cm_g, ln_cm_b, cm_k, cm_v, cm_r,
        gate_w, gate_b, row_w, row_b, col_w, col_b, out, wsf);
}

// Round 4
// 296.163 us; speedup vs baseline: 1.7945x; 1.7945x over previous
//
#include <hip/hip_runtime.h>
#include <math.h>

// B=4, L=32, HP=32, H=64, W=64, D=32, DFFN=64
// Structure: the only true recurrence in the RWKV scan is the 15-op WKV state
// chain. Everything else (LN1+r/k/v, and y/LN2/channel-mix) is per-layer
// parallel and fused into the surrounding throughput kernels.
//   k1: stats + in_proj + LN1 + r/k/v projections   [4096 blocks]
//   k2: WKV recurrence only (per-channel, no LDS)    [16 blocks]
//   k3: y/LN2/cmix + separable mask + merge stream   [4096 blocks]
//   k4: final scalar reduce                          [1 block]
// ws layout (floats): f 131072 | r 131072 | k 131072 | v 131072 | wkv 131072
//                     | gpart 4096 | mpart 4096     (layout [l][b][hp][d])

__device__ __forceinline__ float sigf(float v) { return 1.0f / (1.0f + __expf(-v)); }

// ---------------------------------------------------------------------------
// k1: per-(b,l,hp) stats over a/b, in_proj -> feat, then LN1 + r/k/v matvecs.
// ---------------------------------------------------------------------------
__global__ __launch_bounds__(256) void k_stats(
    const float* __restrict__ x, const float* __restrict__ in_proj_w,
    const float* __restrict__ in_proj_b, const float* __restrict__ layer_emb,
    const float* __restrict__ ln_tm_g, const float* __restrict__ ln_tm_b,
    const float* __restrict__ tm_r, const float* __restrict__ tm_k,
    const float* __restrict__ tm_v,
    float* __restrict__ f_out, float* __restrict__ r_out,
    float* __restrict__ k_out, float* __restrict__ v_out)
{
    __shared__ float red[4][9];
    __shared__ float tot[9];
    __shared__ __align__(16) float xn_s[32];
    const int bid = blockIdx.x;
    const int hp = bid & 31, l = (bid >> 5) & 31, bb = bid >> 10;
    const float4* pa = (const float4*)(x + (size_t)(bb * 2048 + l * 32 + hp) * 4096);
    const float4* pb = (const float4*)(x + (size_t)(bb * 2048 + 1024 + l * 32 + hp) * 4096);
    const int t = threadIdx.x;
    const int gidx = ((l * 4 + bb) * 32 + hp) * 32;

    float sa = 0.f, saa = 0.f, sb = 0.f, sbb = 0.f, sab = 0.f;
    float mna = 3.4e38f, mxa = -3.4e38f, mnb = 3.4e38f, mxb = -3.4e38f;
#pragma unroll
    for (int it = 0; it < 4; ++it) {
        float4 a4 = pa[t + it * 256];
        float4 b4 = pb[t + it * 256];
        sa  += a4.x + a4.y + a4.z + a4.w;
        sb  += b4.x + b4.y + b4.z + b4.w;
        saa += a4.x * a4.x + a4.y * a4.y + a4.z * a4.z + a4.w * a4.w;
        sbb += b4.x * b4.x + b4.y * b4.y + b4.z * b4.z + b4.w * b4.w;
        sab += a4.x * b4.x + a4.y * b4.y + a4.z * b4.z + a4.w * b4.w;
        mna = fminf(mna, fminf(fminf(a4.x, a4.y), fminf(a4.z, a4.w)));
        mxa = fmaxf(mxa, fmaxf(fmaxf(a4.x, a4.y), fmaxf(a4.z, a4.w)));
        mnb = fminf(mnb, fminf(fminf(b4.x, b4.y), fminf(b4.z, b4.w)));
        mxb = fmaxf(mxb, fmaxf(fmaxf(b4.x, b4.y), fmaxf(b4.z, b4.w)));
    }
#pragma unroll
    for (int m = 1; m < 64; m <<= 1) {
        sa  += __shfl_xor(sa, m);
        saa += __shfl_xor(saa, m);
        sb  += __shfl_xor(sb, m);
        sbb += __shfl_xor(sbb, m);
        sab += __shfl_xor(sab, m);
        mna = fminf(mna, __shfl_xor(mna, m));
        mxa = fmaxf(mxa, __shfl_xor(mxa, m));
        mnb = fminf(mnb, __shfl_xor(mnb, m));
        mxb = fmaxf(mxb, __shfl_xor(mxb, m));
    }
    const int lane = t & 63, wv = t >> 6;
    if (lane == 0) {
        red[wv][0] = sa;  red[wv][1] = saa; red[wv][2] = sb;  red[wv][3] = sbb;
        red[wv][4] = sab; red[wv][5] = mna; red[wv][6] = mxa; red[wv][7] = mnb;
        red[wv][8] = mxb;
    }
    __syncthreads();
    if (t == 0) {
#pragma unroll
        for (int q = 0; q < 5; ++q) tot[q] = red[0][q] + red[1][q] + red[2][q] + red[3][q];
        tot[5] = fminf(fminf(red[0][5], red[1][5]), fminf(red[2][5], red[3][5]));
        tot[6] = fmaxf(fmaxf(red[0][6], red[1][6]), fmaxf(red[2][6], red[3][6]));
        tot[7] = fminf(fminf(red[0][7], red[1][7]), fminf(red[2][7], red[3][7]));
        tot[8] = fmaxf(fmaxf(red[0][8], red[1][8]), fmaxf(red[2][8], red[3][8]));
    }
    __syncthreads();
    if (t < 32) {
        const float SA = tot[0], SAA = tot[1], SB = tot[2], SBB = tot[3], SAB = tot[4];
        const float inv_n = 1.f / 4096.f, inv_nm1 = 1.f / 4095.f;
        float st[12];
        st[0] = SA * inv_n;
        st[1] = sqrtf(fmaxf(SAA - SA * SA * inv_n, 0.f) * inv_nm1);
        st[2] = tot[5]; st[3] = tot[6];
        st[4] = SB * inv_n;
        st[5] = sqrtf(fmaxf(SBB - SB * SB * inv_n, 0.f) * inv_nm1);
        st[6] = tot[7]; st[7] = tot[8];
        const float SD = SA - SB, SDD = SAA - 2.f * SAB + SBB;
        st[8]  = SD * inv_n;
        st[9]  = sqrtf(fmaxf(SDD - SD * SD * inv_n, 0.f) * inv_nm1);
        st[10] = sqrtf(fmaxf(SDD, 0.f));
        const float na = fmaxf(sqrtf(SAA), 1e-8f), nb2 = fmaxf(sqrtf(SBB), 1e-8f);
        st[11] = SAB / (na * nb2);
        float fv = in_proj_b[t] + layer_emb[l * 32 + t];
#pragma unroll
        for (int s2 = 0; s2 < 12; ++s2) fv += st[s2] * in_proj_w[t * 12 + s2];
        f_out[gidx + t] = fv;
        // LN1 across the 32 channels (lanes 0..31 of wave 0)
        float s = fv, q = fv * fv;
#pragma unroll
        for (int m = 1; m < 32; m <<= 1) { s += __shfl_xor(s, m, 32); q += __shfl_xor(q, m, 32); }
        const float mu = s * (1.f / 32.f);
        const float var = fmaxf(q * (1.f / 32.f) - mu * mu, 0.f);
        xn_s[t] = (fv - mu) * rsqrtf(var + 1e-5f) * ln_tm_g[t] + ln_tm_b[t];
    }
    __syncthreads();
    // r/k/v projections: threads 0..95, one output dot each
    if (t < 96) {
        const int d = t & 31;
        const float* wrow = (t < 32 ? tm_r : (t < 64 ? tm_k : tm_v)) + d * 32;
        const float4* w4 = (const float4*)wrow;
        const float4* x4 = (const float4*)xn_s;
        float a0 = 0.f, a1 = 0.f, a2 = 0.f, a3 = 0.f;
#pragma unroll
        for (int jq = 0; jq < 2; ++jq) {
            float4 w, xv;
            w = w4[jq];     xv = x4[jq];     a0 += w.x*xv.x + w.y*xv.y + w.z*xv.z + w.w*xv.w;
            w = w4[jq + 2]; xv = x4[jq + 2]; a1 += w.x*xv.x + w.y*xv.y + w.z*xv.z + w.w*xv.w;
            w = w4[jq + 4]; xv = x4[jq + 4]; a2 += w.x*xv.x + w.y*xv.y + w.z*xv.z + w.w*xv.w;
            w = w4[jq + 6]; xv = x4[jq + 6]; a3 += w.x*xv.x + w.y*xv.y + w.z*xv.z + w.w*xv.w;
        }
        const float dot = (a0 + a1) + (a2 + a3);
        if (t < 32)      r_out[gidx + d] = sigf(dot);
        else if (t < 64) k_out[gidx + d] = dot;
        else             v_out[gidx + d] = dot;
    }
}

// ---------------------------------------------------------------------------
// k2: WKV recurrence only. 4096 independent channels (b,hp,d); per-lane
// dependency chain of ~15 ops/layer, k/v prefetched one layer ahead.
// ---------------------------------------------------------------------------
__global__ __launch_bounds__(256) void k_wkv(
    const float* __restrict__ k_in, const float* __restrict__ v_in,
    const float* __restrict__ time_decay, const float* __restrict__ time_first,
    float* __restrict__ wkv_out)
{
    const int ch = blockIdx.x * 256 + threadIdx.x;   // (bb*32+hp)*32+d
    const int d = ch & 31;
    const float tf = time_first[d];
    const float wd = __expf(time_decay[d]);
    float aa = 0.f, bbs = 0.f, pp = -1e30f;
    float kc = k_in[ch], vc = v_in[ch];
#pragma unroll 4
    for (int l = 0; l < 32; ++l) {
        float kn = 0.f, vn = 0.f;
        if (l < 31) { kn = k_in[(l + 1) * 4096 + ch]; vn = v_in[(l + 1) * 4096 + ch]; }
        const float ww = tf + kc;
        const float p = fmaxf(pp, ww);
        const float e1 = __expf(pp - p), e2 = __expf(ww - p);
        wkv_out[l * 4096 + ch] = (e1 * aa + e2 * vc) / fmaxf(e1 * bbs + e2, 1e-8f);
        const float ww2 = pp - wd;
        const float p2 = fmaxf(ww2, kc);
        const float e1b = __expf(ww2 - p2), e2b = __expf(kc - p2);
        aa = e1b * aa + e2b * vc;
        bbs = e1b * bbs + e2b;
        pp = p2;
        kc = kn; vc = vn;
    }
}

// ---------------------------------------------------------------------------
// k3: y = f + r*(wkv@tm_out) -> LN2 -> channel-mix -> feats, then separable
// mask (gate/row/col dots) and the streaming merge. 4096 blocks x 256.
// ---------------------------------------------------------------------------
__global__ __launch_bounds__(256) void k_merge(
    const float* __restrict__ x,
    const float* __restrict__ f_in, const float* __restrict__ r_in,
    const float* __restrict__ wkv_in,
    const float* __restrict__ tm_out,
    const float* __restrict__ ln_cm_g, const float* __restrict__ ln_cm_b,
    const float* __restrict__ cm_k, const float* __restrict__ cm_v,
    const float* __restrict__ cm_r,
    const float* __restrict__ gate_w, const float* __restrict__ gate_b,
    const float* __restrict__ row_w, const float* __restrict__ row_b,
    const float* __restrict__ col_w, const float* __restrict__ col_b,
    float* __restrict__ out, float* __restrict__ gpart, float* __restrict__ mpart)
{
    __shared__ __align__(16) float wkv_s[32];
    __shared__ __align__(16) float xn2_s[32];
    __shared__ __align__(16) float kk_s[64];
    __shared__ float cr_s[32];
    __shared__ float fs[32];          // final feats (y2)
    __shared__ float row_s[64], col_s[64];
    __shared__ float gate_sh;
    __shared__ float red2[4];
    const int bid = blockIdx.x;
    const int hp = bid & 31, l = (bid >> 5) & 31, bb = bid >> 10;
    const int t = threadIdx.x;
    const int gidx = ((l * 4 + bb) * 32 + hp) * 32;

    if (t < 32) wkv_s[t] = wkv_in[gidx + t];
    __syncthreads();
    float yv = 0.f;                    // live only on t<32
    if (t < 32) {
        const float fv = f_in[gidx + t];
        const float rv = r_in[gidx + t];
        const float4* w4 = (const float4*)(tm_out + t * 32);
        const float4* x4 = (const float4*)wkv_s;
        float a0 = 0.f, a1 = 0.f, a2 = 0.f, a3 = 0.f;
#pragma unroll
        for (int jq = 0; jq < 2; ++jq) {
            float4 w, xv;
            w = w4[jq];     xv = x4[jq];     a0 += w.x*xv.x + w.y*xv.y + w.z*xv.z + w.w*xv.w;
            w = w4[jq + 2]; xv = x4[jq + 2]; a1 += w.x*xv.x + w.y*xv.y + w.z*xv.z + w.w*xv.w;
            w = w4[jq + 4]; xv = x4[jq + 4]; a2 += w.x*xv.x + w.y*xv.y + w.z*xv.z + w.w*xv.w;
            w = w4[jq + 6]; xv = x4[jq + 6]; a3 += w.x*xv.x + w.y*xv.y + w.z*xv.z + w.w*xv.w;
        }
        yv = fv + rv * ((a0 + a1) + (a2 + a3));
        // LN2 across lanes 0..31 of wave 0
        float s = yv, q = yv * yv;
#pragma unroll
        for (int m = 1; m < 32; m <<= 1) { s += __shfl_xor(s, m, 32); q += __shfl_xor(q, m, 32); }
        const float mu = s * (1.f / 32.f);
        const float var = fmaxf(q * (1.f / 32.f) - mu * mu, 0.f);
        xn2_s[t] = (yv - mu) * rsqrtf(var + 1e-5f) * ln_cm_g[t] + ln_cm_b[t];
    }
    __syncthreads();
    if (t < 64) {        // kk[e] = relu(xn2 @ cm_k[e])^2
        const float4* w4 = (const float4*)(cm_k + t * 32);
        const float4* x4 = (const float4*)xn2_s;
        float a0 = 0.f, a1 = 0.f, a2 = 0.f, a3 = 0.f;
#pragma unroll
        for (int jq = 0; jq < 2; ++jq) {
            float4 w, xv;
            w = w4[jq];     xv = x4[jq];     a0 += w.x*xv.x + w.y*xv.y + w.z*xv.z + w.w*xv.w;
            w = w4[jq + 2]; xv = x4[jq + 2]; a1 += w.x*xv.x + w.y*xv.y + w.z*xv.z + w.w*xv.w;
            w = w4[jq + 4]; xv = x4[jq + 4]; a2 += w.x*xv.x + w.y*xv.y + w.z*xv.z + w.w*xv.w;
            w = w4[jq + 6]; xv = x4[jq + 6]; a3 += w.x*xv.x + w.y*xv.y + w.z*xv.z + w.w*xv.w;
        }
        float kk = fmaxf((a0 + a1) + (a2 + a3), 0.f);
        kk_s[t] = kk * kk;
    } else if (t < 96) { // cr[d] = sigmoid(xn2 @ cm_r[d])
        const int d = t - 64;
        const float4* w4 = (const float4*)(cm_r + d * 32);
        const float4* x4 = (const float4*)xn2_s;
        float a0 = 0.f, a1 = 0.f, a2 = 0.f, a3 = 0.f;
#pragma unroll
        for (int jq = 0; jq < 2; ++jq) {
            float4 w, xv;
            w = w4[jq];     xv = x4[jq];     a0 += w.x*xv.x + w.y*xv.y + w.z*xv.z + w.w*xv.w;
            w = w4[jq + 2]; xv = x4[jq + 2]; a1 += w.x*xv.x + w.y*xv.y + w.z*xv.z + w.w*xv.w;
            w = w4[jq + 4]; xv = x4[jq + 4]; a2 += w.x*xv.x + w.y*xv.y + w.z*xv.z + w.w*xv.w;
            w = w4[jq + 6]; xv = x4[jq + 6]; a3 += w.x*xv.x + w.y*xv.y + w.z*xv.z + w.w*xv.w;
        }
        cr_s[d] = sigf((a0 + a1) + (a2 + a3));
    }
    __syncthreads();
    if (t < 32) {        // y2 = y + cr * (kk @ cm_v[d])
        const float4* w4 = (const float4*)(cm_v + t * 64);
        const float4* x4 = (const float4*)kk_s;
        float a0 = 0.f, a1 = 0.f, a2 = 0.f, a3 = 0.f;
#pragma unroll
        for (int jq = 0; jq < 4; ++jq) {
            float4 w, xv;
            w = w4[jq];      xv = x4[jq];      a0 += w.x*xv.x + w.y*xv.y + w.z*xv.z + w.w*xv.w;
            w = w4[jq + 4];  xv = x4[jq + 4];  a1 += w.x*xv.x + w.y*xv.y + w.z*xv.z + w.w*xv.w;
            w = w4[jq + 8];  xv = x4[jq + 8];  a2 += w.x*xv.x + w.y*xv.y + w.z*xv.z + w.w*xv.w;
            w = w4[jq + 12]; xv = x4[jq + 12]; a3 += w.x*xv.x + w.y*xv.y + w.z*xv.z + w.w*xv.w;
        }
        fs[t] = yv + cr_s[t] * ((a0 + a1) + (a2 + a3));
    }
    __syncthreads();
    // ---- separable mask dots ----
    if (t < 64) {
        float a0 = row_b[t], a1 = 0.f, a2 = 0.f, a3 = 0.f;
#pragma unroll
        for (int d2 = 0; d2 < 8; ++d2) {
            a0 += fs[d2]      * row_w[t * 32 + d2];
            a1 += fs[d2 + 8]  * row_w[t * 32 + d2 + 8];
            a2 += fs[d2 + 16] * row_w[t * 32 + d2 + 16];
            a3 += fs[d2 + 24] * row_w[t * 32 + d2 + 24];
        }
        row_s[t] = (a0 + a1) + (a2 + a3);
    } else if (t < 128) {
        const int w = t - 64;
        float a0 = col_b[w], a1 = 0.f, a2 = 0.f, a3 = 0.f;
#pragma unroll
        for (int d2 = 0; d2 < 8; ++d2) {
            a0 += fs[d2]      * col_w[w * 32 + d2];
            a1 += fs[d2 + 8]  * col_w[w * 32 + d2 + 8];
            a2 += fs[d2 + 16] * col_w[w * 32 + d2 + 16];
            a3 += fs[d2 + 24] * col_w[w * 32 + d2 + 24];
        }
        col_s[w] = (a0 + a1) + (a2 + a3);
    } else if (t == 128) {
        float acc = gate_b[0];
#pragma unroll
        for (int d2 = 0; d2 < 32; ++d2) acc += fs[d2] * gate_w[d2];
        gate_sh = acc;
    }
    __syncthreads();
    const float gate = gate_sh;
    const float4* pa = (const float4*)(x + (size_t)(bb * 2048 + l * 32 + hp) * 4096);
    const float4* pb = (const float4*)(x + (size_t)(bb * 2048 + 1024 + l * 32 + hp) * 4096);
    float4* po = (float4*)(out + (size_t)(bb * 1024 + l * 32 + hp) * 4096);

    float msum = 0.f;
#pragma unroll
    for (int it = 0; it < 4; ++it) {
        const int i = t + it * 256;
        const float4 a4 = pa[i];
        const float4 b4 = pb[i];
        const int h = i >> 4, w0 = (i & 15) * 4;
        const float gr = gate + row_s[h];
        const float m0 = sigf(gr + col_s[w0 + 0]);
        const float m1 = sigf(gr + col_s[w0 + 1]);
        const float m2 = sigf(gr + col_s[w0 + 2]);
        const float m3 = sigf(gr + col_s[w0 + 3]);
        float4 o;
        o.x = b4.x + m0 * (a4.x - b4.x);
        o.y = b4.y + m1 * (a4.y - b4.y);
        o.z = b4.z + m2 * (a4.z - b4.z);
        o.w = b4.w + m3 * (a4.w - b4.w);
        po[i] = o;
        msum += m0 + m1 + m2 + m3;
    }
#pragma unroll
    for (int m = 1; m < 64; m <<= 1) msum += __shfl_xor(msum, m);
    if ((t & 63) == 0) red2[t >> 6] = msum;
    __syncthreads();
    if (t == 0) {
        mpart[bid] = red2[0] + red2[1] + red2[2] + red2[3];
        gpart[bid] = sigf(gate);
    }
}

// ---------------------------------------------------------------------------
// k4: reduce 4096 per-block partials into the two scalar outputs.
// ---------------------------------------------------------------------------
__global__ __launch_bounds__(256) void k_final(
    const float* __restrict__ gpart, const float* __restrict__ mpart,
    float* __restrict__ out)
{
    __shared__ float rg[4], rm[4];
    const int t = threadIdx.x;
    float gs = 0.f, ms = 0.f;
    for (int i = t; i < 4096; i += 256) { gs += gpart[i]; ms += mpart[i]; }
#pragma unroll
    for (int m = 1; m < 64; m <<= 1) { gs += __shfl_xor(gs, m); ms += __shfl_xor(ms, m); }
    if ((t & 63) == 0) { rg[t >> 6] = gs; rm[t >> 6] = ms; }
    __syncthreads();
    if (t == 0) {
        out[16777216] = (rg[0] + rg[1] + rg[2] + rg[3]) * (1.f / 4096.f);
        out[16777217] = (rm[0] + rm[1] + rm[2] + rm[3]) * (1.f / 16777216.f);
    }
}

extern "C" void kernel_launch(void* const* d_in, const int* in_sizes, int n_in,
                              void* d_out, int out_size, void* d_ws, size_t ws_size,
                              hipStream_t stream) {
    const float* x          = (const float*)d_in[0];
    const float* in_proj_w  = (const float*)d_in[1];
    const float* in_proj_b  = (const float*)d_in[2];
    const float* layer_emb  = (const float*)d_in[3];
    const float* time_decay = (const float*)d_in[4];
    const float* time_first = (const float*)d_in[5];
    const float* ln_tm_g    = (const float*)d_in[6];
    const float* ln_tm_b    = (const float*)d_in[7];
    const float* tm_r       = (const float*)d_in[8];
    const float* tm_k       = (const float*)d_in[9];
    const float* tm_v       = (const float*)d_in[10];
    const float* tm_out     = (const float*)d_in[11];
    const float* ln_cm_g    = (const float*)d_in[12];
    const float* ln_cm_b    = (const float*)d_in[13];
    const float* cm_k       = (const float*)d_in[14];
    const float* cm_v       = (const float*)d_in[15];
    const float* cm_r       = (const float*)d_in[16];
    const float* gate_w     = (const float*)d_in[17];
    const float* gate_b     = (const float*)d_in[18];
    const float* row_w      = (const float*)d_in[19];
    const float* row_b      = (const float*)d_in[20];
    const float* col_w      = (const float*)d_in[21];
    const float* col_b      = (const float*)d_in[22];
    float* out = (float*)d_out;

    float* wsf   = (float*)d_ws;
    float* f_ws   = wsf;               // 131072  [l][b][hp][d]
    float* r_ws   = wsf + 131072;      // 131072
    float* k_ws   = wsf + 262144;      // 131072
    float* v_ws   = wsf + 393216;      // 131072
    float* wkv_ws = wsf + 524288;      // 131072
    float* gpart  = wsf + 655360;      // 4096
    float* mpart  = wsf + 659456;      // 4096

    k_stats<<<dim3(4096), dim3(256), 0, stream>>>(
        x, in_proj_w, in_proj_b, layer_emb, ln_tm_g, ln_tm_b,
        tm_r, tm_k, tm_v, f_ws, r_ws, k_ws, v_ws);
    k_wkv<<<dim3(16), dim3(256), 0, stream>>>(k_ws, v_ws, time_decay, time_first, wkv_ws);
    k_merge<<<dim3(4096), dim3(256), 0, stream>>>(
        x, f_ws, r_ws, wkv_ws, tm_out, ln_cm_g, ln_cm_b, cm_k, cm_v, cm_r,
        gate_w, gate_b, row_w, row_b, col_w, col_b, out, gpart, mpart);
    k_final<<<dim3(1), dim3(256), 0, stream>>>(gpart, mpart, out);
}